// Round 6
// baseline (78.236 us; speedup 1.0000x reference)
//
#include <hip/hip_runtime.h>

// NALU B=1024, I=512, O=512 — SINGLE fused dispatch, fp16 MFMA 16x16x32.
//   w1 = tanh(w_hat)*sigmoid(m_hat); a = x@w1; s = log(max(|x|,eps))@w1
//   m1 = exp(min(s,20)); out = g1*a + (1-g1)*m1*clip(ms,-1,1)
// s ~ N(-143,11^2) => m1 underflows to 0; guarded exactly: any s > -80
// takes a cold path computing the true sign-product from wh/mh.
//
// vs R4's failed fusion: (1) 2 blocks/CU (512 blocks, 50 KB LDS), not 1;
// (2) B staged via coalesced row-major float4 reads -> LDS transposed tile
//     -> strided u16 fragment gather (no 2KB-strided global gathers);
// (3) A staged fragment-ordered in LDS (16B/lane b128, m97-class pattern).
// K in 2 passes of 256. B-frags pre-gathered to VGPRs per pass so the MFMA
// loop is pure ds_read_b128 + MFMA.
// Frag layouts (learn_hip-verified): A[m=lane&15][k=(lane>>4)*8+j],
// B[k=(lane>>4)*8+j][n=lane&15], D[m=(lane>>4)*4+reg][n=lane&15].

#define O_N 512
#define I_N 512
#define B_N 1024
#define KH  256          // K per pass
#define BTP 36           // raw B tile row = 32 f16 + 4 pad = 72 B (8B-aligned)

typedef _Float16 f16;
typedef _Float16 f16x4 __attribute__((ext_vector_type(4)));
typedef _Float16 f16x8 __attribute__((ext_vector_type(8)));
typedef float f32x4 __attribute__((ext_vector_type(4)));

__device__ __forceinline__ float fast_sigmoid(float v) {
    return 1.0f / (1.0f + __expf(-v));
}
__device__ __forceinline__ float fast_tanh(float v) {
    return 1.0f - 2.0f / (1.0f + __expf(2.0f * v));   // exact at both tails
}

__global__ __launch_bounds__(256) void nalu_fused_kernel(const float* __restrict__ x,
                                                         const float* __restrict__ wh,
                                                         const float* __restrict__ mh,
                                                         const float* __restrict__ g,
                                                         float* __restrict__ out) {
    __shared__ f16x8 lax[2][8][64];   // 16 KB  A frags (x),     [tm][tk][lane]
    __shared__ f16x8 lal[2][8][64];   // 16 KB  A frags (log|x|)
    __shared__ f16   bt[KH][BTP];     // 18 KB  raw w1 tile, transposed-readable

    const int tid  = threadIdx.x;
    const int lane = tid & 63;
    const int w    = tid >> 6;
    const int wm   = w & 1;                  // b-half of block tile
    const int wn   = w >> 1;                 // o-half of block tile
    const int o0g  = blockIdx.x * 32;
    const int b0   = blockIdx.y * 32;

    f32x4 ca = {0.f, 0.f, 0.f, 0.f}, cs = ca;

    for (int kh = 0; kh < 2; ++kh) {
        const int kbase = kh * KH;

        // ---- stage A frags: 1024 positions/pass, 4 per thread.
        // Fragment-order global reads of x (k-contiguous rows, R5-prep pattern),
        // conflict-free 16B/lane LDS writes.
#pragma unroll
        for (int r = 0; r < 4; ++r) {
            const int f  = r * 256 + tid;
            const int fl = f & 63;
            const int tk = (f >> 6) & 7;
            const int tm = f >> 9;                       // 0..1
            const int m  = b0 + tm * 16 + (fl & 15);
            const int k0 = kbase + tk * 32 + (fl >> 4) * 8;
            const float4* x4 = (const float4*)(x + m * I_N + k0);
            const float4 q0 = x4[0], q1 = x4[1];
            const float vx[8] = {q0.x, q0.y, q0.z, q0.w, q1.x, q1.y, q1.z, q1.w};
            f16x8 fx, fv;
#pragma unroll
            for (int j = 0; j < 8; ++j) {
                fx[j] = (f16)vx[j];
                fv[j] = (f16)__logf(fmaxf(fabsf(vx[j]), 1e-7f));
            }
            lax[tm][tk][fl] = fx;
            lal[tm][tk][fl] = fv;
        }

        // ---- stage B raw tile: 256k x 32o of w1, coalesced float4 row reads.
        // thread: k-local = i*32 + (tid>>3), n0 = (tid&7)*4 -> one aligned b64.
#pragma unroll
        for (int i = 0; i < 8; ++i) {
            const int kl = i * 32 + (tid >> 3);
            const int n0 = (tid & 7) * 4;
            const int idx = (kbase + kl) * O_N + o0g + n0;
            const float4 wa = *(const float4*)(wh + idx);
            const float4 ma = *(const float4*)(mh + idx);
            f16x4 bv;
            bv[0] = (f16)(fast_tanh(wa.x) * fast_sigmoid(ma.x));
            bv[1] = (f16)(fast_tanh(wa.y) * fast_sigmoid(ma.y));
            bv[2] = (f16)(fast_tanh(wa.z) * fast_sigmoid(ma.z));
            bv[3] = (f16)(fast_tanh(wa.w) * fast_sigmoid(ma.w));
            *(f16x4*)&bt[kl][n0] = bv;
        }

        __syncthreads();

        // ---- pre-gather this wave's B frags for the pass (32 VGPRs)
        const int nl = wn * 16 + (lane & 15);
        const int kq = (lane >> 4) * 8;
        f16x8 bf[8];
#pragma unroll
        for (int tk = 0; tk < 8; ++tk) {
#pragma unroll
            for (int j = 0; j < 8; ++j)
                bf[tk][j] = bt[tk * 32 + kq + j][nl];
        }

        // ---- MFMA over this K-half: pure b128 + MFMA
#pragma unroll
        for (int tk = 0; tk < 8; ++tk) {
            const f16x8 ax = lax[wm][tk][lane];
            const f16x8 al = lal[wm][tk][lane];
            ca = __builtin_amdgcn_mfma_f32_16x16x32_f16(ax, bf[tk], ca, 0, 0, 0);
            cs = __builtin_amdgcn_mfma_f32_16x16x32_f16(al, bf[tk], cs, 0, 0, 0);
        }

        __syncthreads();   // LDS reused next pass
    }

    // ---- epilogue: D[m=(lane>>4)*4+r][n=lane&15]
    const int col = lane & 15;
    const int rq  = (lane >> 4) * 4;
    const int o   = o0g + wn * 16 + col;
    const int bb  = b0 + wm * 16 + rq;
    const float g1  = fast_sigmoid(g[o]);
    const float omg = 1.0f - g1;
#pragma unroll
    for (int r = 0; r < 4; ++r) {
        const int b = bb + r;
        const float sv = cs[r];
        const float m1 = __expf(fminf(sv, 20.0f));
        float msv = 1.0f;
        if (sv > -80.0f) {                  // cold path (expected never): exact ms
            float p = 1.0f;
            for (int i = 0; i < I_N; ++i) {
                // ws_oi[o][i] = |w1.flat[o*I+i]| = |w1[row=o][col=i]|
                const float wv = fabsf(fast_tanh(wh[o * I_N + i]) *
                                       fast_sigmoid(mh[o * I_N + i]));
                const float xv = x[b * I_N + i];
                const float sg = (xv > 0.f) ? 1.f : ((xv < 0.f) ? -1.f : 0.f);
                p *= sg * wv + (1.0f - wv);
            }
            msv = fminf(fmaxf(p, -1.0f), 1.0f);
        }
        out[b * O_N + o] = g1 * ca[r] + omg * m1 * msv;
    }
}

extern "C" void kernel_launch(void* const* d_in, const int* in_sizes, int n_in,
                              void* d_out, int out_size, void* d_ws, size_t ws_size,
                              hipStream_t stream) {
    const float* x  = (const float*)d_in[0];   // [B, I]
    const float* wh = (const float*)d_in[1];   // [I, O]
    const float* mh = (const float*)d_in[2];   // [I, O]
    const float* g  = (const float*)d_in[3];   // [O]
    float* out = (float*)d_out;                // [B, O] fp32

    (void)d_ws; (void)ws_size;                 // scratch unused (fill cost is harness-fixed)

    nalu_fused_kernel<<<dim3(O_N / 32, B_N / 32), 256, 0, stream>>>(x, wh, mh, g, out);
}

// Round 7
// 69.265 us; speedup vs baseline: 1.1295x; 1.1295x over previous
//
#include <hip/hip_runtime.h>

// NALU B=1024, I=512, O=512 — two dispatches, fp16 MFMA 16x16x32.
//   w1 = tanh(w_hat)*sigmoid(m_hat); a = x@w1; s = log(max(|x|,eps))@w1
//   m1 = exp(min(s,20)); out = g1*a + (1-g1)*m1*clip(ms,-1,1)
// s ~ N(-143,11^2) => m1 underflows to 0; guarded exactly: any s > -80
// takes a cold path computing the true sign-product from wh/mh.
//
// R7 change vs R5: main splits the a- and s-GEMMs across WAVES (a-wave
// computes x@w1, s-wave computes logx@w1 for the same 16b x 16o tile,
// result combined via 2KB LDS at the epilogue). Work per wave halves =>
// 4096 waves = 4 waves/SIMD (was 2) => 2x latency hiding on the L2/L3
// fragment loads, which R5/R6 decomposition says dominate the main kernel.
// Prep is byte-identical to R5 (proven correct + adequate).
// Frag layouts (learn_hip-verified): A[m=lane&15][k=(lane>>4)*8+j],
// B[k=(lane>>4)*8+j][n=lane&15], D[m=(lane>>4)*4+reg][n=lane&15].

#define O_N 512
#define I_N 512
#define B_N 1024

typedef _Float16 f16;
typedef _Float16 f16x8 __attribute__((ext_vector_type(8)));
typedef float f32x4 __attribute__((ext_vector_type(4)));

__device__ __forceinline__ float fast_sigmoid(float v) {
    return 1.0f / (1.0f + __expf(-v));
}
__device__ __forceinline__ float fast_tanh(float v) {
    return 1.0f - 2.0f / (1.0f + __expf(2.0f * v));   // exact at both tails
}

// ---- prep (R5-identical): blocks 0..127 = B frags, 128..383 = A frags ----
__global__ __launch_bounds__(256) void prep_kernel(const float* __restrict__ x,
                                                   const float* __restrict__ wh,
                                                   const float* __restrict__ mh,
                                                   f16x8* __restrict__ apx,
                                                   f16x8* __restrict__ apl,
                                                   f16x8* __restrict__ bp) {
    const int tid = threadIdx.x;
    if (blockIdx.x < 128) {
        __shared__ f16 lt[32][72];          // w1 tile [k][n]
        const int kb = blockIdx.x >> 3;     // 0..15  (k-tile of 32)
        const int nb = blockIdx.x & 7;      // 0..7   (n-tile of 64)
        const int r  = tid >> 3;
        const int c0 = (tid & 7) * 8;
        const int base = (kb * 32 + r) * O_N + nb * 64 + c0;
        const float4* w4 = (const float4*)(wh + base);
        const float4* m4 = (const float4*)(mh + base);
        const float4 wa = w4[0], wb = w4[1], ma = m4[0], mb = m4[1];
        f16x8 row;
        row[0] = (f16)(fast_tanh(wa.x) * fast_sigmoid(ma.x));
        row[1] = (f16)(fast_tanh(wa.y) * fast_sigmoid(ma.y));
        row[2] = (f16)(fast_tanh(wa.z) * fast_sigmoid(ma.z));
        row[3] = (f16)(fast_tanh(wa.w) * fast_sigmoid(ma.w));
        row[4] = (f16)(fast_tanh(wb.x) * fast_sigmoid(mb.x));
        row[5] = (f16)(fast_tanh(wb.y) * fast_sigmoid(mb.y));
        row[6] = (f16)(fast_tanh(wb.z) * fast_sigmoid(mb.z));
        row[7] = (f16)(fast_tanh(wb.w) * fast_sigmoid(mb.w));
        *(f16x8*)&lt[r][c0] = row;
        __syncthreads();
        const int fl  = tid & 63;
        const int tnl = tid >> 6;
        const int nl  = tnl * 16 + (fl & 15);
        const int k0  = (fl >> 4) * 8;
        f16x8 bf;
#pragma unroll
        for (int j = 0; j < 8; ++j) bf[j] = lt[k0 + j][nl];
        const int tn_g = nb * 4 + tnl;
        bp[tn_g * 1024 + kb * 64 + fl] = bf;
    } else {
        const int t  = (blockIdx.x - 128) * 256 + tid;
        const int fl = t & 63;
        const int tk = (t >> 6) & 15;
        const int tm = t >> 10;
        const int m  = tm * 16 + (fl & 15);
        const int k0 = tk * 32 + (fl >> 4) * 8;
        const float4* x4 = (const float4*)(x + m * I_N + k0);
        const float4 q0 = x4[0], q1 = x4[1];
        const float vx[8] = {q0.x, q0.y, q0.z, q0.w, q1.x, q1.y, q1.z, q1.w};
        f16x8 fx, fv;
#pragma unroll
        for (int j = 0; j < 8; ++j) {
            fx[j] = (f16)vx[j];
            fv[j] = (f16)__logf(fmaxf(fabsf(vx[j]), 1e-7f));
        }
        apx[t] = fx;
        apl[t] = fv;
    }
}

// ---- main: grid (16,64) = 1024 blocks, 4 waves each = 4096 waves (4/SIMD).
// Block tile 16b x 32o. Wave w: stream = w&1 (0:a from x, 1:s from log|x|),
// o-subtile = w>>1. s-wave passes its 16x16 result to the a-wave via LDS.
__global__ __launch_bounds__(256, 4) void nalu_mfma_kernel(const f16x8* __restrict__ apx,
                                                           const f16x8* __restrict__ apl,
                                                           const f16x8* __restrict__ bp,
                                                           const float* __restrict__ g,
                                                           const float* __restrict__ x,
                                                           const float* __restrict__ wh,
                                                           const float* __restrict__ mh,
                                                           float* __restrict__ out) {
    __shared__ float scs[2][16][17];         // s-results, +1 pad

    const int lane = threadIdx.x & 63;
    const int w    = threadIdx.x >> 6;
    const int isS  = w & 1;
    const int osub = w >> 1;
    const int b0   = blockIdx.y * 16;
    const int o0   = blockIdx.x * 32 + osub * 16;
    const int tm   = blockIdx.y;
    const int tn   = o0 >> 4;

    f32x4 acc = {0.f, 0.f, 0.f, 0.f};

    const f16x8* pa = (isS ? apl : apx) + tm * 1024 + lane;
    const f16x8* pb = bp + tn * 1024 + lane;

#pragma unroll 8
    for (int tk = 0; tk < 16; ++tk) {
        const f16x8 av = pa[tk * 64];
        const f16x8 bv = pb[tk * 64];
        acc = __builtin_amdgcn_mfma_f32_16x16x32_f16(av, bv, acc, 0, 0, 0);
    }

    // D[m=(lane>>4)*4+r][n=lane&15]
    const int col = lane & 15;
    const int rq  = (lane >> 4) * 4;

    if (isS) {
#pragma unroll
        for (int r = 0; r < 4; ++r) scs[osub][rq + r][col] = acc[r];
    }
    __syncthreads();

    if (!isS) {
        const int o = o0 + col;
        const float g1  = fast_sigmoid(g[o]);
        const float omg = 1.0f - g1;
#pragma unroll
        for (int r = 0; r < 4; ++r) {
            const int b = b0 + rq + r;
            const float sv = scs[osub][rq + r][col];
            const float m1 = __expf(fminf(sv, 20.0f));
            float msv = 1.0f;
            if (sv > -80.0f) {              // cold path (expected never): exact ms
                float p = 1.0f;
                for (int i = 0; i < I_N; ++i) {
                    // ws_oi[o][i] = |w1.flat[o*I+i]| = |w1[row=o][col=i]|
                    const float wv = fabsf(fast_tanh(wh[o * I_N + i]) *
                                           fast_sigmoid(mh[o * I_N + i]));
                    const float xv = x[b * I_N + i];
                    const float sg = (xv > 0.f) ? 1.f : ((xv < 0.f) ? -1.f : 0.f);
                    p *= sg * wv + (1.0f - wv);
                }
                msv = fminf(fmaxf(p, -1.0f), 1.0f);
            }
            out[b * O_N + o] = g1 * acc[r] + omg * m1 * msv;
        }
    }
}

extern "C" void kernel_launch(void* const* d_in, const int* in_sizes, int n_in,
                              void* d_out, int out_size, void* d_ws, size_t ws_size,
                              hipStream_t stream) {
    const float* x  = (const float*)d_in[0];   // [B, I]
    const float* wh = (const float*)d_in[1];   // [I, O]
    const float* mh = (const float*)d_in[2];   // [I, O]
    const float* g  = (const float*)d_in[3];   // [O]
    float* out = (float*)d_out;                // [B, O] fp32

    char* ws = (char*)d_ws;
    f16x8* apx = (f16x8*)ws;                          // 1 MB  (64*16*64 frags)
    f16x8* apl = (f16x8*)(ws + (1u << 20));           // 1 MB
    f16x8* bp  = (f16x8*)(ws + (2u << 20));           // 512 KB (32*16*64 frags)

    prep_kernel<<<384, 256, 0, stream>>>(x, wh, mh, apx, apl, bp);
    nalu_mfma_kernel<<<dim3(16, 64), 256, 0, stream>>>(apx, apl, bp, g, x, wh, mh, out);
}